// Round 2
// baseline (175.312 us; speedup 1.0000x reference)
//
#include <hip/hip_runtime.h>

#define LDIM 1024
#define NSHIFT 10
#define ROW_V (LDIM / 4)   // 256 int4 per row

__global__ __launch_bounds__(256) void chunk_mask_kernel(
    const int* __restrict__ mask, int4* __restrict__ outv, int total_v)
{
    const int stride = gridDim.x * blockDim.x;
    for (int f = blockIdx.x * blockDim.x + threadIdx.x; f < total_v; f += stride) {
        const int i  = (f >> 8) & (LDIM - 1);   // row within L
        const int j0 = (f & (ROW_V - 1)) << 2;  // first of 4 columns

        int4 v = make_int4(0, 0, 0, 0);

        // band [i-10, i+10] intersects [j0, j0+3] ?
        if (j0 + 3 >= i - NSHIFT && j0 <= i + NSHIFT) {
            const int b = f >> 18;              // f / (1024 * 256)
            const int* __restrict__ mrow = mask + b * LDIM;
#pragma unroll
            for (int u = 0; u < 4; ++u) {
                const int j = j0 + u;
                const int d = j - i;
                if (d >= -NSHIFT && d <= NSHIFT) {
                    const int lo = (d < 0) ? j : i;
                    const int hi = (d < 0) ? i : j;
                    int s = 0;
                    for (int k = lo + 1; k <= hi; ++k) s += mrow[k];
                    ((int*)&v)[u] = (s == 0) ? 1 : 0;
                }
            }
        }
        outv[f] = v;
    }
}

extern "C" void kernel_launch(void* const* d_in, const int* in_sizes, int n_in,
                              void* d_out, int out_size, void* d_ws, size_t ws_size,
                              hipStream_t stream) {
    const int* mask = (const int*)d_in[0];
    int4* outv = (int4*)d_out;
    const int total_v = out_size / 4;   // int4 elements: 8,388,608

    // 2048 blocks x 256 threads = 8 blocks/CU, 16 int4 stores per thread
    chunk_mask_kernel<<<2048, 256, 0, stream>>>(mask, outv, total_v);
}

// Round 3
// 137.440 us; speedup vs baseline: 1.2755x; 1.2755x over previous
//
#include <hip/hip_runtime.h>

#define LDIM 1024
#define NSHIFT 10
#define ROW_V (LDIM / 4)          // 256 int4 per row
#define BATCH_V (LDIM * ROW_V)    // 262144 int4 per batch (2^18)

// Pre-pass: for each (b,i) compute 21 band bits.
// bit (NSHIFT + d), d in [-10,10]:  out[b, i, i+d]
__global__ __launch_bounds__(256) void band_prepass(
    const int* __restrict__ mask, unsigned int* __restrict__ bandtab, int n)
{
    const int idx = blockIdx.x * blockDim.x + threadIdx.x;  // (b<<10)|i
    if (idx >= n) return;
    const int b = idx >> 10;
    const int i = idx & (LDIM - 1);
    const int* __restrict__ mrow = mask + b * LDIM;

    unsigned int bits = 1u << NSHIFT;   // d = 0 (diagonal) always 1
    int prod = 1;
#pragma unroll
    for (int d = 1; d <= NSHIFT; ++d) { // backward: j = i-d, need mask[(j,i]] all 0
        const int k = i - d + 1;
        const int mv = (k >= 1) ? mrow[k] : 1;   // j<0 -> force 0
        prod &= (mv == 0) ? 1 : 0;
        bits |= ((unsigned int)prod) << (NSHIFT - d);
    }
    prod = 1;
#pragma unroll
    for (int d = 1; d <= NSHIFT; ++d) { // forward: j = i+d, need mask[(i,j]] all 0
        const int k = i + d;
        const int mv = (k < LDIM) ? mrow[k] : 1; // j>1023 -> force 0
        prod &= (mv == 0) ? 1 : 0;
        bits |= ((unsigned int)prod) << (NSHIFT + d);
    }
    bandtab[idx] = bits;
}

__global__ __launch_bounds__(256) void chunk_mask_fill(
    const unsigned int* __restrict__ bandtab, int4* __restrict__ outv, int total_v)
{
    const int stride = gridDim.x * blockDim.x;
    const int f0 = blockIdx.x * blockDim.x + threadIdx.x;
    // stride is a multiple of BATCH_V/16 with (stride>>8)&1023 == 0:
    // i and j0 are invariant across grid-stride iterations.
    const int i  = (f0 >> 8) & (LDIM - 1);
    const int j0 = (f0 & (ROW_V - 1)) << 2;

    const bool in_band = (j0 + 3 >= i - NSHIFT) && (j0 <= i + NSHIFT);

    if (!__any(in_band)) {
        // wave-uniform pure fill path — identical structure to rocclr fill
        const int4 z = make_int4(0, 0, 0, 0);
        for (int f = f0; f < total_v; f += stride) outv[f] = z;
    } else {
        const int base = j0 - i + NSHIFT;   // bit index for u=0
        for (int f = f0; f < total_v; f += stride) {
            const int b = f >> 18;
            const unsigned int bits = bandtab[(b << 10) | i];  // L1/L2-hot broadcast
            int4 v;
            v.x = (base     >= 0 && base     <= 2 * NSHIFT) ? (int)((bits >> (base    )) & 1u) : 0;
            v.y = (base + 1 >= 0 && base + 1 <= 2 * NSHIFT) ? (int)((bits >> (base + 1)) & 1u) : 0;
            v.z = (base + 2 >= 0 && base + 2 <= 2 * NSHIFT) ? (int)((bits >> (base + 2)) & 1u) : 0;
            v.w = (base + 3 >= 0 && base + 3 <= 2 * NSHIFT) ? (int)((bits >> (base + 3)) & 1u) : 0;
            outv[f] = v;
        }
    }
}

extern "C" void kernel_launch(void* const* d_in, const int* in_sizes, int n_in,
                              void* d_out, int out_size, void* d_ws, size_t ws_size,
                              hipStream_t stream) {
    const int* mask = (const int*)d_in[0];
    int4* outv = (int4*)d_out;
    unsigned int* bandtab = (unsigned int*)d_ws;   // 128 KB used

    const int B = in_sizes[0] / LDIM;              // 32
    const int n_rows = B * LDIM;                   // 32768
    const int total_v = out_size / 4;              // 8,388,608 int4

    band_prepass<<<(n_rows + 255) / 256, 256, 0, stream>>>(mask, bandtab, n_rows);
    chunk_mask_fill<<<2048, 256, 0, stream>>>(bandtab, outv, total_v);
}